// Round 11
// baseline (486.607 us; speedup 1.0000x reference)
//
#include <hip/hip_runtime.h>
#include <hip/hip_bf16.h>

constexpr int IN_ = 256, H_ = 128, HN_ = 4;
constexpr int S_ = 5, B_ = 1024, M_ = 16, D_ = 512;

typedef __attribute__((ext_vector_type(8))) short bf16x8;
typedef __attribute__((ext_vector_type(4))) float f32x4;
typedef __attribute__((ext_vector_type(4))) short s16x4;

__device__ __forceinline__ float lrelu(float z) { return z >= 0.f ? z : 0.2f * z; }
__device__ __forceinline__ short f2b(float f) {            // RNE f32->bf16
    unsigned u = __float_as_uint(f);
    u += 0x7FFF + ((u >> 16) & 1);
    return (short)(u >> 16);
}
__device__ __forceinline__ float b2f(short s) {
    return __uint_as_float(((unsigned)(unsigned short)s) << 16);
}

// ---------------------------------------------------------------------------
// MFMA frag conventions (mfma_f32_16x16x32_bf16):
// A-frag: row = lane&15, k = (lane>>4)*8 + j.  B-frag: B[k][n]=W[n][k] -> 16B/lane.
// C/D: col = lane&15, row = (lane>>4)*4 + i.
// LDS tiles XOR-swizzled: element (r,c) at r*LD + (c ^ ((r&7)<<3)), granule 8 shorts.
// ---------------------------------------------------------------------------

// per-wave 16xK @ Kx128 GEMM, A in LDS (16 rows), full 128 cols. (k_target)
template<int K, int ACT, bool TLDS, bool TGLB>
__device__ __forceinline__ void gemm_ldsA(
    const short* A, const short* __restrict__ W, const float* __restrict__ bias,
    short* C_lds, short* __restrict__ C_glob, int lane)
{
    f32x4 acc[8];
#pragma unroll
    for (int i = 0; i < 8; ++i) acc[i] = (f32x4){0.f, 0.f, 0.f, 0.f};
    const int m16 = lane & 15;
    const int kg  = (lane >> 4) * 8;
    const short* Ab = A + m16 * K;
    const int aswz = (m16 & 7) << 3;
#pragma unroll
    for (int kk = 0; kk < K; kk += 32) {
        bf16x8 afr = *(const bf16x8*)(Ab + ((kk + kg) ^ aswz));
        const short* Wb = W + (size_t)m16 * K + kk + kg;
#pragma unroll
        for (int cb = 0; cb < 8; ++cb) {
            bf16x8 bf = *(const bf16x8*)(Wb + (size_t)cb * 16 * K);
            acc[cb] = __builtin_amdgcn_mfma_f32_16x16x32_bf16(afr, bf, acc[cb], 0, 0, 0);
        }
    }
    const int r0 = (lane >> 4) * 4;
#pragma unroll
    for (int cb = 0; cb < 8; ++cb) {
        const int col = cb * 16 + m16;
        const float bv = bias ? bias[col] : 0.f;
#pragma unroll
        for (int i = 0; i < 4; ++i) {
            const int r = r0 + i;
            float v = acc[cb][i] + bv;
            if (ACT) v = lrelu(v);
            const short bs = f2b(v);
            if (TLDS) C_lds[r * H_ + (col ^ ((r & 7) << 3))] = bs;
            if (TGLB) C_glob[(size_t)r * H_ + col] = bs;
        }
    }
}

// 32-row x 32-col wave sub-GEMM, K=256, A-frags from GLOBAL bf16 rows
// (xr0/xr1 = per-lane row pointers, already offset by kg).
template<int ACT>
__device__ __forceinline__ void tile_gemm256g(
    const short* __restrict__ xr0, const short* __restrict__ xr1,
    const short* __restrict__ W, const float* __restrict__ bias,
    short* Cdst, int lane, int rbase, int colb)
{
    f32x4 acc[2][2];
#pragma unroll
    for (int a = 0; a < 2; ++a)
#pragma unroll
        for (int b = 0; b < 2; ++b) acc[a][b] = (f32x4){0.f, 0.f, 0.f, 0.f};
    const int m16 = lane & 15, kg = (lane >> 4) * 8;
#pragma unroll
    for (int kk = 0; kk < 8; ++kk) {
        const int k0 = kk * 32 + kg;
        bf16x8 af0 = *(const bf16x8*)(xr0 + kk * 32);
        bf16x8 af1 = *(const bf16x8*)(xr1 + kk * 32);
#pragma unroll
        for (int cbl = 0; cbl < 2; ++cbl) {
            const int col = colb + cbl * 16 + m16;
            bf16x8 bf = *(const bf16x8*)(W + (size_t)col * 256 + k0);
            acc[0][cbl] = __builtin_amdgcn_mfma_f32_16x16x32_bf16(af0, bf, acc[0][cbl], 0, 0, 0);
            acc[1][cbl] = __builtin_amdgcn_mfma_f32_16x16x32_bf16(af1, bf, acc[1][cbl], 0, 0, 0);
        }
    }
#pragma unroll
    for (int cbl = 0; cbl < 2; ++cbl) {
        const int col = colb + cbl * 16 + m16;
        const float bv = bias[col];
#pragma unroll
        for (int rg = 0; rg < 2; ++rg)
#pragma unroll
            for (int i = 0; i < 4; ++i) {
                const int row = rbase + rg * 16 + (lane >> 4) * 4 + i;
                float v = acc[rg][cbl][i] + bv;
                if (ACT) v = lrelu(v);
                Cdst[row * 128 + (col ^ ((row & 7) << 3))] = f2b(v);
            }
    }
}

// 32-row x 32-col wave sub-GEMM, K=128, A in LDS [64][128] swz.
template<int ACT>
__device__ __forceinline__ void tile_gemm128(
    const short* Asrc, const short* __restrict__ W, const float* __restrict__ bias,
    short* Cdst, int lane, int rbase, int colb)
{
    f32x4 acc[2][2];
#pragma unroll
    for (int a = 0; a < 2; ++a)
#pragma unroll
        for (int b = 0; b < 2; ++b) acc[a][b] = (f32x4){0.f, 0.f, 0.f, 0.f};
    const int m16 = lane & 15, kg = (lane >> 4) * 8;
#pragma unroll
    for (int kk = 0; kk < 4; ++kk) {
        const int k0 = kk * 32 + kg;
        bf16x8 af[2];
#pragma unroll
        for (int rg = 0; rg < 2; ++rg) {
            const int row = rbase + rg * 16 + m16;
            af[rg] = *(const bf16x8*)(Asrc + row * 128 + (k0 ^ ((row & 7) << 3)));
        }
#pragma unroll
        for (int cbl = 0; cbl < 2; ++cbl) {
            const int col = colb + cbl * 16 + m16;
            bf16x8 bf = *(const bf16x8*)(W + (size_t)col * 128 + k0);
#pragma unroll
            for (int rg = 0; rg < 2; ++rg)
                acc[rg][cbl] = __builtin_amdgcn_mfma_f32_16x16x32_bf16(af[rg], bf, acc[rg][cbl], 0, 0, 0);
        }
    }
#pragma unroll
    for (int cbl = 0; cbl < 2; ++cbl) {
        const int col = colb + cbl * 16 + m16;
        const float bv = bias[col];
#pragma unroll
        for (int rg = 0; rg < 2; ++rg)
#pragma unroll
            for (int i = 0; i < 4; ++i) {
                const int row = rbase + rg * 16 + (lane >> 4) * 4 + i;
                float v = acc[rg][cbl][i] + bv;
                if (ACT) v = lrelu(v);
                Cdst[row * 128 + (col ^ ((row & 7) << 3))] = f2b(v);
            }
    }
}

// ---- f32->bf16 weight conversion (7 tensors) ----
__global__ __launch_bounds__(256) void k_convert(
    const float* f0, const float* f1, const float* f2, const float* f3,
    const float* f4, const float* f5, const float* f6,
    short* g0, short* g1, short* g2, short* g3, short* g4, short* g5, short* g6)
{
    const float* s; short* d; int n;
    switch (blockIdx.y) {
        case 0: s = f0; d = g0; n = 655360; break;
        case 1: s = f1; d = g1; n = 327680; break;
        case 2: s = f2; d = g2; n = 327680; break;
        case 3: s = f3; d = g3; n = 327680; break;
        case 4: s = f4; d = g4; n = 131072; break;
        case 5: s = f5; d = g5; n = 131072; break;
        default: s = f6; d = g6; n = 131072; break;
    }
    int i = (blockIdx.x * 256 + threadIdx.x) * 4;
    if (i >= n) return;
    float4 v = *(const float4*)(s + i);
    s16x4 p; p.x = f2b(v.x); p.y = f2b(v.y); p.z = f2b(v.z); p.w = f2b(v.w);
    *(s16x4*)(d + i) = p;
}

// ---- x f32 -> bf16 copy (20000*256 = 5,120,000 elems) ----
__global__ __launch_bounds__(256) void k_convert_x(
    const float* __restrict__ x, short* __restrict__ xb)
{
    int i = (blockIdx.x * 256 + threadIdx.x) * 4;
    if (i >= 5120000) return;
    float4 v = *(const float4*)(x + i);
    s16x4 p; p.x = f2b(v.x); p.y = f2b(v.y); p.z = f2b(v.z); p.w = f2b(v.w);
    *(s16x4*)(xb + i) = p;
}

// ---- transpose ip1w [2][128][512] -> [2][512][128], bp1w [128][512] -> [512][128] (f32) ----
__global__ __launch_bounds__(256) void k_transpose(
    const float* __restrict__ ip1w, const float* __restrict__ bp1w,
    float* __restrict__ ipT, float* __restrict__ bpT)
{
    int i = blockIdx.x * 256 + threadIdx.x;
    if (i < 131072) {
        const int d = i & 511, hk = i >> 9;       // hk = ki*128 + h
        const int ki = hk >> 7, h = hk & 127;
        ipT[ki * 65536 + d * 128 + h] = ip1w[i];
    } else if (i < 131072 + 65536) {
        const int j = i - 131072;
        const int d = j & 511, h = j >> 9;
        bpT[d * 128 + h] = bp1w[j];
    }
}

// ---- K1: target chain. Block = (16 targets, s); 4 waves = 4 heads, shared A. ----
__global__ __launch_bounds__(256) void k_target(
    const float* __restrict__ x, const int* __restrict__ tgt,
    const short* __restrict__ wb_fc, const float* __restrict__ fc_b,
    const short* __restrict__ wb_q,  const float* __restrict__ q_b,
    const short* __restrict__ wb_a2, const float* __restrict__ a2_b,
    const short* __restrict__ wb_aW,
    short* __restrict__ x_shb, short* __restrict__ wh2b)
{
    const int t = threadIdx.x, lane = t & 63, w = t >> 6;
    const int bt = blockIdx.x, s = blockIdx.y;
    const int km = (s < 2) ? 0 : 1;
    const int b0 = bt * 16;
    const int sh = s * HN_ + w, kh = km * HN_ + w;   // wave w = head w

    __shared__ __align__(16) short A[16 * 256];      // 8 KB shared across heads
    __shared__ __align__(16) short BUF[4 * 2048];    // 4 KB per wave: Y->Q->H2
    short* buf0 = BUF + w * 2048;

    // gather 16 target rows (f32 -> bf16, swizzled); 16 threads per row
    {
        const int row = t >> 4, q4 = t & 15;
        const int g = tgt[b0 + row];
        const float* xr = x + (size_t)g * IN_ + q4 * 16;
        short* arow = A + row * 256;
        const int key = (row & 7) << 3;
#pragma unroll
        for (int j = 0; j < 4; ++j) {
            float4 u = *(const float4*)(xr + j * 4);
            const int c = q4 * 16 + j * 4;
            s16x4 p; p.x = f2b(u.x); p.y = f2b(u.y); p.z = f2b(u.z); p.w = f2b(u.w);
            *(s16x4*)(arow + (c ^ key)) = p;
        }
    }
    __syncthreads();

    gemm_ldsA<256, 1, true, true>(A, wb_fc + (size_t)sh * 32768, fc_b + sh * H_,
                                  buf0, x_shb + ((size_t)sh * B_ + b0) * H_, lane);
    gemm_ldsA<128, 0, true, false>(buf0, wb_q + (size_t)sh * 16384, q_b + sh * H_,
                                   buf0, nullptr, lane);
    gemm_ldsA<128, 1, true, false>(buf0, wb_a2 + (size_t)kh * 16384, a2_b + kh * H_,
                                   buf0, nullptr, lane);
    gemm_ldsA<128, 0, false, true>(buf0, wb_aW + (size_t)kh * 16384, nullptr,
                                   nullptr, wh2b + ((size_t)sh * B_ + b0) * H_, lane);
}

// ---- K2: fused neighbor pipeline. Block = (64 rows, s); 8 waves (2x4); A from global. ----
__global__ __launch_bounds__(512) void k_fused(
    const short* __restrict__ xb, const int* __restrict__ nbr,
    const short* __restrict__ wb_fc, const float* __restrict__ fc_b,
    const short* __restrict__ wb_k,  const float* __restrict__ k_b,
    const short* __restrict__ wb_v,  const float* __restrict__ v_b,
    const short* __restrict__ wb_a1, const float* __restrict__ a1_b,
    const short* __restrict__ x_shb, const short* __restrict__ wh2b,
    float* __restrict__ out_sbd)
{
    const int t = threadIdx.x, lane = t & 63, w = t >> 6;   // 8 waves
    const int bt = blockIdx.x, s = blockIdx.y;
    const int km = (s < 2) ? 0 : 1;
    const int r0 = bt * 64;           // global row base (row = b*16+m)
    const int b0 = bt * 4;            // 4 targets per block
    const int wr = w >> 2;            // row half
    const int wc = w & 3;             // col group

    __shared__ __align__(16) short Yt[64 * 128];   // 16 KB (Y, then H1)
    __shared__ __align__(16) short KH[64 * 128];   // 16 KB
    __shared__ __align__(16) short VH[64 * 128];   // 16 KB
    __shared__ int nid[64];                        // 256 B

    if (t < 64) nid[t] = nbr[(size_t)s * (B_ * M_) + r0 + t];
    __syncthreads();

    const int rbase = wr * 32, colb = wc * 32;
    const int m16 = lane & 15, kg = (lane >> 4) * 8;
    // per-lane global A-row pointers (constant across heads; L1-resident after head 0)
    const short* xr0 = xb + (size_t)nid[rbase + m16] * 256 + kg;
    const short* xr1 = xb + (size_t)nid[rbase + 16 + m16] * 256 + kg;

    for (int h = 0; h < HN_; ++h) {
        const int sh = s * HN_ + h, kh = km * HN_ + h;

        // G1: Y = lrelu(fc(x_nbr))  (A-frags straight from global)
        tile_gemm256g<1>(xr0, xr1, wb_fc + (size_t)sh * 32768, fc_b + sh * H_,
                         Yt, lane, rbase, colb);
        __syncthreads();
        // G2: Kh = k(Y); G3: Vh = v(Y)
        tile_gemm128<0>(Yt, wb_k + (size_t)sh * 16384, k_b + sh * H_, KH, lane, rbase, colb);
        tile_gemm128<0>(Yt, wb_v + (size_t)sh * 16384, v_b + sh * H_, VH, lane, rbase, colb);
        __syncthreads();
        // G4: H1 = lrelu(a1(Kh)) -> Yt (dead after G2/G3; no in-place hazard)
        tile_gemm128<1>(KH, wb_a1 + (size_t)kh * 16384, a1_b + kh * H_, Yt, lane, rbase, colb);
        __syncthreads();

        // scores + softmax + PV + merge. Wave w: b = b0 + (w&3), d-half = w>>2.
        {
            const int b_loc = w & 3, dhalf = w >> 2;
            const int b = b0 + b_loc;
            const short* wrow = wh2b + ((size_t)sh * B_ + b) * H_;
            const int mloc = lane >> 2;              // 0..15
            const int row  = b_loc * 16 + mloc;
            const int key  = (mloc & 7) << 3;        // (b_loc*16)&7 == 0
            float sc = 0.f;
#pragma unroll
            for (int j8 = 0; j8 < 4; ++j8) {
                const int c = (lane & 3) * 32 + j8 * 8;
                bf16x8 hv = *(const bf16x8*)(Yt + row * 128 + (c ^ key));   // H1
                bf16x8 wv = *(const bf16x8*)(wrow + c);
#pragma unroll
                for (int e2 = 0; e2 < 8; ++e2) sc += b2f(hv[e2]) * b2f(wv[e2]);
            }
            sc += __shfl_xor(sc, 1);
            sc += __shfl_xor(sc, 2);                 // quad holds score for m=mloc
            float mx = sc;
            mx = fmaxf(mx, __shfl_xor(mx, 4));
            mx = fmaxf(mx, __shfl_xor(mx, 8));
            mx = fmaxf(mx, __shfl_xor(mx, 16));
            mx = fmaxf(mx, __shfl_xor(mx, 32));
            const float es = expf(sc - mx);
            float ss = es;
            ss += __shfl_xor(ss, 4);
            ss += __shfl_xor(ss, 8);
            ss += __shfl_xor(ss, 16);
            ss += __shfl_xor(ss, 32);                // sum of one es per quad
            const float inv = 1.f / ss;

            const short* xrow = x_shb + ((size_t)sh * B_ + b) * H_;
            float* orow = out_sbd + ((size_t)s * B_ + b) * D_ + h * H_;
            const int d = dhalf * 64 + lane;
            float hacc = 0.f;
#pragma unroll
            for (int mm = 0; mm < 16; ++mm) {
                const float e_mm = __shfl(es, mm * 4) * inv;
                const float vv = b2f(VH[(b_loc * 16 + mm) * 128 + (d ^ ((mm & 7) << 3))]);
                hacc += lrelu(vv * e_mm);
            }
            orow[d] = (b2f(xrow[d]) + hacc) * 0.5f;
        }
        __syncthreads();   // protect Yt/KH/VH before next head
    }
}

// ---- K3: semantic attention, transposed-weight coalesced version ----
__global__ __launch_bounds__(256) void k_semantic(
    const float* __restrict__ out_sbd,
    const float* __restrict__ ipT, const float* __restrict__ ip1b,
    const float* __restrict__ ip2w,
    const float* __restrict__ bpT, const float* __restrict__ bp1b,
    const float* __restrict__ bp2w,
    float* __restrict__ out)
{
    const int b = blockIdx.x, t = threadIdx.x;
    const int h = t & 127, dh = t >> 7;       // thread = (h, d-half)
    __shared__ float zs[S_ * D_];             // 10 KB
    __shared__ float red[2 * 128 * 8];        // 8 KB (dh, h, p-slot)
    __shared__ float mps[2 * D_];             // 4 KB
    __shared__ float svals[8];
    __shared__ float beta_s[8];

    for (int idx = t; idx < S_ * D_ / 4; idx += 256) {
        int sidx = idx >> 7, c = idx & 127;
        ((float4*)zs)[idx] = ((const float4*)(out_sbd + ((size_t)sidx * B_ + b) * D_))[c];
    }
    __syncthreads();

    {
        float a0 = 0.f, a1 = 0.f, a2 = 0.f, a3 = 0.f, a4 = 0.f;
        const float* w0 = ipT + h;            // [d][h], stride 128
        const float* w1 = ipT + 65536 + h;
        const int dbeg = dh * 256;
        for (int d = dbeg; d < dbeg + 256; ++d) {
            const float wv0 = w0[d * 128];
            const float wv1 = w1[d * 128];
            a0 += wv0 * zs[d];
            a1 += wv0 * zs[512 + d];
            a2 += wv1 * zs[1024 + d];
            a3 += wv1 * zs[1536 + d];
            a4 += wv1 * zs[2048 + d];
        }
        float* rr = red + (dh * 128 + h) * 8;
        rr[0] = a0; rr[1] = a1; rr[2] = a2; rr[3] = a3; rr[4] = a4;
    }
    __syncthreads();
    if (t < 128) {
#pragma unroll
        for (int p = 0; p < 5; ++p) {
            const int ki = (p < 2) ? 0 : 1;
            float tot = red[t * 8 + p] + red[(128 + t) * 8 + p] + ip1b[ki * 128 + t];
            red[t * 8 + p] = tanhf(tot) * ip2w[ki * 128 + t];
        }
    }
    __syncthreads();
    if (t < 64) {
#pragma unroll
        for (int p = 0; p < 5; ++p) {
            float v = red[t * 8 + p] + red[(t + 64) * 8 + p];
            v += __shfl_xor(v, 1);  v += __shfl_xor(v, 2);  v += __shfl_xor(v, 4);
            v += __shfl_xor(v, 8);  v += __shfl_xor(v, 16); v += __shfl_xor(v, 32);
            if (t == 0) svals[p] = v;
        }
    }
    __syncthreads();
    if (t == 0) {
        float mx = fmaxf(svals[0], svals[1]);
        float e0 = expf(svals[0] - mx), e1 = expf(svals[1] - mx);
        float iv = 1.f / (e0 + e1);
        beta_s[0] = e0 * iv; beta_s[1] = e1 * iv;
        mx = fmaxf(fmaxf(svals[2], svals[3]), svals[4]);
        e0 = expf(svals[2] - mx); e1 = expf(svals[3] - mx); float e2 = expf(svals[4] - mx);
        iv = 1.f / (e0 + e1 + e2);
        beta_s[2] = e0 * iv; beta_s[3] = e1 * iv; beta_s[4] = e2 * iv;
    }
    __syncthreads();
    for (int d = t; d < D_; d += 256) {
        mps[d]       = beta_s[0] * zs[d]        + beta_s[1] * zs[512 + d];
        mps[512 + d] = beta_s[2] * zs[1024 + d] + beta_s[3] * zs[1536 + d] + beta_s[4] * zs[2048 + d];
    }
    __syncthreads();

    {
        float c0 = 0.f, c1 = 0.f;
        const float* wb = bpT + h;
        const int dbeg = dh * 256;
        for (int d = dbeg; d < dbeg + 256; ++d) {
            const float wv = wb[d * 128];
            c0 += wv * mps[d];
            c1 += wv * mps[512 + d];
        }
        float* rr = red + (dh * 128 + h) * 8;
        rr[0] = c0; rr[1] = c1;
    }
    __syncthreads();
    if (t < 128) {
#pragma unroll
        for (int p = 0; p < 2; ++p) {
            float tot = red[t * 8 + p] + red[(128 + t) * 8 + p] + bp1b[t];
            red[t * 8 + p] = tanhf(tot) * bp2w[t];
        }
    }
    __syncthreads();
    if (t < 64) {
#pragma unroll
        for (int p = 0; p < 2; ++p) {
            float v = red[t * 8 + p] + red[(t + 64) * 8 + p];
            v += __shfl_xor(v, 1);  v += __shfl_xor(v, 2);  v += __shfl_xor(v, 4);
            v += __shfl_xor(v, 8);  v += __shfl_xor(v, 16); v += __shfl_xor(v, 32);
            if (t == 0) svals[p] = v;
        }
    }
    __syncthreads();
    if (t == 0) {
        float mx = fmaxf(svals[0], svals[1]);
        float e0 = expf(svals[0] - mx), e1 = expf(svals[1] - mx);
        float iv = 1.f / (e0 + e1);
        beta_s[0] = e0 * iv; beta_s[1] = e1 * iv;
    }
    __syncthreads();
    for (int d = t; d < D_; d += 256)
        out[(size_t)b * D_ + d] = beta_s[0] * mps[d] + beta_s[1] * mps[512 + d];
}

extern "C" void kernel_launch(void* const* d_in, const int* in_sizes, int n_in,
                              void* d_out, int out_size, void* d_ws, size_t ws_size,
                              hipStream_t stream)
{
    const float* x    = (const float*)d_in[0];
    const int*   tgt  = (const int*)d_in[1];
    const int*   nbr  = (const int*)d_in[2];
    const float* fc_w = (const float*)d_in[3];
    const float* fc_b = (const float*)d_in[4];
    const float* q_w  = (const float*)d_in[5];
    const float* q_b  = (const float*)d_in[6];
    const float* k_w  = (const float*)d_in[7];
    const float* k_b  = (const float*)d_in[8];
    const float* v_w  = (const float*)d_in[9];
    const float* v_b  = (const float*)d_in[10];
    const float* attW = (const float*)d_in[11];
    const float* a1w  = (const float*)d_in[12];
    const float* a1b  = (const float*)d_in[13];
    const float* a2w  = (const float*)d_in[14];
    const float* a2b  = (const float*)d_in[15];
    const float* ip1w = (const float*)d_in[16];
    const float* ip1b = (const float*)d_in[17];
    const float* ip2w = (const float*)d_in[18];
    const float* bp1w = (const float*)d_in[19];
    const float* bp1b = (const float*)d_in[20];
    const float* bp2w = (const float*)d_in[21];

    float* out = (float*)d_out;

    // ws layout (shorts unless noted)
    short* wb_fc = (short*)d_ws;               // 655,360  (S,HN,H,IN)
    short* wb_q  = wb_fc + 655360;             // 327,680  (S,HN,H,H)
    short* wb_k  = wb_q + 327680;
    short* wb_v  = wb_k + 327680;
    short* wb_aW = wb_v + 327680;              // 131,072  (K,HN,H,H)
    short* wb_a1 = wb_aW + 131072;
    short* wb_a2 = wb_a1 + 131072;
    short* x_shb = wb_a2 + 131072;             // 2,621,440 (S,HN,B,H)
    short* wh2b  = x_shb + 2621440;            // 2,621,440
    float* out_sbd = (float*)(wh2b + 2621440); // 2,621,440 f32 (S,B,D)
    float* ipT   = out_sbd + 2621440;          // 131,072 f32
    float* bpT   = ipT + 131072;               // 65,536 f32
    short* xb    = (short*)(bpT + 65536);      // 5,120,000 shorts (x as bf16)

    k_convert<<<dim3(640, 7), 256, 0, stream>>>(
        fc_w, q_w, k_w, v_w, attW, a1w, a2w,
        wb_fc, wb_q, wb_k, wb_v, wb_aW, wb_a1, wb_a2);
    k_convert_x<<<dim3(5000), 256, 0, stream>>>(x, xb);
    k_transpose<<<dim3(768), 256, 0, stream>>>(ip1w, bp1w, ipT, bpT);
    k_target<<<dim3(64, 5), 256, 0, stream>>>(
        x, tgt, wb_fc, fc_b, wb_q, q_b, wb_a2, a2b, wb_aW, x_shb, wh2b);
    k_fused<<<dim3(256, 5), 512, 0, stream>>>(
        xb, nbr, wb_fc, fc_b, wb_k, k_b, wb_v, v_b, wb_a1, a1b, x_shb, wh2b, out_sbd);
    k_semantic<<<dim3(B_), 256, 0, stream>>>(
        out_sbd, ipT, ip1b, ip2w, bpT, bp1b, bp2w, out);
}

// Round 12
// 436.356 us; speedup vs baseline: 1.1152x; 1.1152x over previous
//
#include <hip/hip_runtime.h>
#include <hip/hip_bf16.h>

constexpr int IN_ = 256, H_ = 128, HN_ = 4;
constexpr int S_ = 5, B_ = 1024, M_ = 16, D_ = 512;

typedef __attribute__((ext_vector_type(8))) short bf16x8;
typedef __attribute__((ext_vector_type(4))) float f32x4;
typedef __attribute__((ext_vector_type(4))) short s16x4;

__device__ __forceinline__ float lrelu(float z) { return z >= 0.f ? z : 0.2f * z; }
__device__ __forceinline__ short f2b(float f) {            // RNE f32->bf16
    unsigned u = __float_as_uint(f);
    u += 0x7FFF + ((u >> 16) & 1);
    return (short)(u >> 16);
}
__device__ __forceinline__ float b2f(short s) {
    return __uint_as_float(((unsigned)(unsigned short)s) << 16);
}

// ---------------------------------------------------------------------------
// MFMA frag conventions (mfma_f32_16x16x32_bf16):
// A-frag: row = lane&15, k = (lane>>4)*8 + j.  B-frag: B[k][n]=W[n][k] -> 16B/lane.
// C/D: col = lane&15, row = (lane>>4)*4 + i.
// LDS tiles XOR-swizzled: element (r,c) at r*LD + (c ^ ((r&7)<<3)), granule 8 shorts.
// ---------------------------------------------------------------------------

// per-wave 16xK @ Kx128 GEMM, A in LDS (16 rows), full 128 cols. (k_target)
template<int K, int ACT, bool TLDS, bool TGLB>
__device__ __forceinline__ void gemm_ldsA(
    const short* A, const short* __restrict__ W, const float* __restrict__ bias,
    short* C_lds, short* __restrict__ C_glob, int lane)
{
    f32x4 acc[8];
#pragma unroll
    for (int i = 0; i < 8; ++i) acc[i] = (f32x4){0.f, 0.f, 0.f, 0.f};
    const int m16 = lane & 15;
    const int kg  = (lane >> 4) * 8;
    const short* Ab = A + m16 * K;
    const int aswz = (m16 & 7) << 3;
#pragma unroll
    for (int kk = 0; kk < K; kk += 32) {
        bf16x8 afr = *(const bf16x8*)(Ab + ((kk + kg) ^ aswz));
        const short* Wb = W + (size_t)m16 * K + kk + kg;
#pragma unroll
        for (int cb = 0; cb < 8; ++cb) {
            bf16x8 bf = *(const bf16x8*)(Wb + (size_t)cb * 16 * K);
            acc[cb] = __builtin_amdgcn_mfma_f32_16x16x32_bf16(afr, bf, acc[cb], 0, 0, 0);
        }
    }
    const int r0 = (lane >> 4) * 4;
#pragma unroll
    for (int cb = 0; cb < 8; ++cb) {
        const int col = cb * 16 + m16;
        const float bv = bias ? bias[col] : 0.f;
#pragma unroll
        for (int i = 0; i < 4; ++i) {
            const int r = r0 + i;
            float v = acc[cb][i] + bv;
            if (ACT) v = lrelu(v);
            const short bs = f2b(v);
            if (TLDS) C_lds[r * H_ + (col ^ ((r & 7) << 3))] = bs;
            if (TGLB) C_glob[(size_t)r * H_ + col] = bs;
        }
    }
}

// 32-row x 32-col wave sub-GEMM, K=256, A in LDS [64][256] swz (rows rbase..+32).
template<int ACT>
__device__ __forceinline__ void tile_gemm256(
    const short* Asrc, const short* __restrict__ W, const float* __restrict__ bias,
    short* Cdst, int lane, int rbase, int colb)
{
    f32x4 acc[2][2];
#pragma unroll
    for (int a = 0; a < 2; ++a)
#pragma unroll
        for (int b = 0; b < 2; ++b) acc[a][b] = (f32x4){0.f, 0.f, 0.f, 0.f};
    const int m16 = lane & 15, kg = (lane >> 4) * 8;
#pragma unroll
    for (int kk = 0; kk < 8; ++kk) {
        const int k0 = kk * 32 + kg;
        bf16x8 af[2];
#pragma unroll
        for (int rg = 0; rg < 2; ++rg) {
            const int row = rbase + rg * 16 + m16;
            af[rg] = *(const bf16x8*)(Asrc + row * 256 + (k0 ^ ((row & 7) << 3)));
        }
#pragma unroll
        for (int cbl = 0; cbl < 2; ++cbl) {
            const int col = colb + cbl * 16 + m16;
            bf16x8 bf = *(const bf16x8*)(W + (size_t)col * 256 + k0);
#pragma unroll
            for (int rg = 0; rg < 2; ++rg)
                acc[rg][cbl] = __builtin_amdgcn_mfma_f32_16x16x32_bf16(af[rg], bf, acc[rg][cbl], 0, 0, 0);
        }
    }
#pragma unroll
    for (int cbl = 0; cbl < 2; ++cbl) {
        const int col = colb + cbl * 16 + m16;
        const float bv = bias[col];
#pragma unroll
        for (int rg = 0; rg < 2; ++rg)
#pragma unroll
            for (int i = 0; i < 4; ++i) {
                const int row = rbase + rg * 16 + (lane >> 4) * 4 + i;
                float v = acc[rg][cbl][i] + bv;
                if (ACT) v = lrelu(v);
                Cdst[row * 128 + (col ^ ((row & 7) << 3))] = f2b(v);
            }
    }
}

// 32-row x 32-col wave sub-GEMM, K=128, A in LDS [64][128] swz. MIDBAR = block
// barrier between compute and write (for safe in-place A overwrite).
template<int ACT, bool MIDBAR>
__device__ __forceinline__ void tile_gemm128(
    const short* Asrc, const short* __restrict__ W, const float* __restrict__ bias,
    short* Cdst, int lane, int rbase, int colb)
{
    f32x4 acc[2][2];
#pragma unroll
    for (int a = 0; a < 2; ++a)
#pragma unroll
        for (int b = 0; b < 2; ++b) acc[a][b] = (f32x4){0.f, 0.f, 0.f, 0.f};
    const int m16 = lane & 15, kg = (lane >> 4) * 8;
#pragma unroll
    for (int kk = 0; kk < 4; ++kk) {
        const int k0 = kk * 32 + kg;
        bf16x8 af[2];
#pragma unroll
        for (int rg = 0; rg < 2; ++rg) {
            const int row = rbase + rg * 16 + m16;
            af[rg] = *(const bf16x8*)(Asrc + row * 128 + (k0 ^ ((row & 7) << 3)));
        }
#pragma unroll
        for (int cbl = 0; cbl < 2; ++cbl) {
            const int col = colb + cbl * 16 + m16;
            bf16x8 bf = *(const bf16x8*)(W + (size_t)col * 128 + k0);
#pragma unroll
            for (int rg = 0; rg < 2; ++rg)
                acc[rg][cbl] = __builtin_amdgcn_mfma_f32_16x16x32_bf16(af[rg], bf, acc[rg][cbl], 0, 0, 0);
        }
    }
    if (MIDBAR) __syncthreads();
#pragma unroll
    for (int cbl = 0; cbl < 2; ++cbl) {
        const int col = colb + cbl * 16 + m16;
        const float bv = bias[col];
#pragma unroll
        for (int rg = 0; rg < 2; ++rg)
#pragma unroll
            for (int i = 0; i < 4; ++i) {
                const int row = rbase + rg * 16 + (lane >> 4) * 4 + i;
                float v = acc[rg][cbl][i] + bv;
                if (ACT) v = lrelu(v);
                Cdst[row * 128 + (col ^ ((row & 7) << 3))] = f2b(v);
            }
    }
}

// ---- f32->bf16 weight conversion (3 tensors: fc, v, attW) ----
__global__ __launch_bounds__(256) void k_convert(
    const float* f0, const float* f1, const float* f2,
    short* g0, short* g1, short* g2)
{
    const float* s; short* d; int n;
    switch (blockIdx.y) {
        case 0: s = f0; d = g0; n = 655360; break;
        case 1: s = f1; d = g1; n = 327680; break;
        default: s = f2; d = g2; n = 131072; break;
    }
    int i = (blockIdx.x * 256 + threadIdx.x) * 4;
    if (i >= n) return;
    float4 v = *(const float4*)(s + i);
    s16x4 p; p.x = f2b(v.x); p.y = f2b(v.y); p.z = f2b(v.z); p.w = f2b(v.w);
    *(s16x4*)(d + i) = p;
}

// ---- weight fusion: ka = a1w@k_w (+bias), qa = a2w@q_w (+bias) per (s,h) ----
// blockIdx.x = sh (0..19), blockIdx.y: 0=ka, 1=qa. 256 threads.
__global__ __launch_bounds__(256) void k_fuse_w(
    const float* __restrict__ a1w, const float* __restrict__ k_w,
    const float* __restrict__ a1b, const float* __restrict__ k_b,
    const float* __restrict__ a2w, const float* __restrict__ q_w,
    const float* __restrict__ a2b, const float* __restrict__ q_b,
    short* __restrict__ wb_ka, float* __restrict__ ka_b,
    short* __restrict__ wb_qa, float* __restrict__ qa_b)
{
    const int sh = blockIdx.x;
    const int s = sh >> 2, h = sh & 3;
    const int kh = ((s < 2) ? 0 : 1) * 4 + h;
    const float *A, *Bm, *bA, *bB; short* oW; float* oB;
    if (blockIdx.y == 0) {
        A = a1w + (size_t)kh * 16384; Bm = k_w + (size_t)sh * 16384;
        bA = a1b + kh * 128; bB = k_b + sh * 128;
        oW = wb_ka + (size_t)sh * 16384; oB = ka_b + sh * 128;
    } else {
        A = a2w + (size_t)kh * 16384; Bm = q_w + (size_t)sh * 16384;
        bA = a2b + kh * 128; bB = q_b + sh * 128;
        oW = wb_qa + (size_t)sh * 16384; oB = qa_b + sh * 128;
    }
    __shared__ float Alt[129 * 128];   // A transposed, +1 pad (bank-conflict-free)
    __shared__ float Bl[128 * 128];
    const int t = threadIdx.x;
    for (int idx = t; idx < 16384; idx += 256) {
        const int o = idx >> 7, j = idx & 127;
        Alt[j * 129 + o] = A[idx];          // coalesced read, padded write
    }
    for (int i = t; i < 4096; i += 256)
        ((float4*)Bl)[i] = ((const float4*)Bm)[i];
    __syncthreads();

    const int o = t & 127, half = t >> 7;
    float acc[64];
#pragma unroll
    for (int i = 0; i < 64; ++i) acc[i] = 0.f;
    for (int j = 0; j < 128; ++j) {
        const float a = Alt[j * 129 + o];               // conflict-free
        const float* brow = Bl + j * 128 + half * 64;   // broadcast
#pragma unroll
        for (int i = 0; i < 64; ++i) acc[i] += a * brow[i];
    }
#pragma unroll
    for (int i = 0; i < 64; ++i) oW[o * 128 + half * 64 + i] = f2b(acc[i]);
    if (half == 0) {
        float sb = bA[o];
        for (int j = 0; j < 128; ++j) sb += Alt[j * 129 + o] * bB[j];
        oB[o] = sb;
    }
}

// ---- transpose ip1w [2][128][512] -> [2][512][128], bp1w -> [512][128] (f32) ----
__global__ __launch_bounds__(256) void k_transpose(
    const float* __restrict__ ip1w, const float* __restrict__ bp1w,
    float* __restrict__ ipT, float* __restrict__ bpT)
{
    int i = blockIdx.x * 256 + threadIdx.x;
    if (i < 131072) {
        const int d = i & 511, hk = i >> 9;
        const int ki = hk >> 7, h = hk & 127;
        ipT[ki * 65536 + d * 128 + h] = ip1w[i];
    } else if (i < 131072 + 65536) {
        const int j = i - 131072;
        const int d = j & 511, h = j >> 9;
        bpT[d * 128 + h] = bp1w[j];
    }
}

// ---- K1: target chain (fc -> qa(lrelu) -> aW). 4 waves = 4 heads, shared A. ----
__global__ __launch_bounds__(256) void k_target(
    const float* __restrict__ x, const int* __restrict__ tgt,
    const short* __restrict__ wb_fc, const float* __restrict__ fc_b,
    const short* __restrict__ wb_qa, const float* __restrict__ qa_b,
    const short* __restrict__ wb_aW,
    short* __restrict__ x_shb, short* __restrict__ wh2b)
{
    const int t = threadIdx.x, lane = t & 63, w = t >> 6;
    const int bt = blockIdx.x, s = blockIdx.y;
    const int km = (s < 2) ? 0 : 1;
    const int b0 = bt * 16;
    const int sh = s * HN_ + w, kh = km * HN_ + w;

    __shared__ __align__(16) short A[16 * 256];
    __shared__ __align__(16) short BUF[4 * 2048];
    short* buf0 = BUF + w * 2048;

    {
        const int row = t >> 4, q4 = t & 15;
        const int g = tgt[b0 + row];
        const float* xr = x + (size_t)g * IN_ + q4 * 16;
        short* arow = A + row * 256;
        const int key = (row & 7) << 3;
#pragma unroll
        for (int j = 0; j < 4; ++j) {
            float4 u = *(const float4*)(xr + j * 4);
            const int c = q4 * 16 + j * 4;
            s16x4 p; p.x = f2b(u.x); p.y = f2b(u.y); p.z = f2b(u.z); p.w = f2b(u.w);
            *(s16x4*)(arow + (c ^ key)) = p;
        }
    }
    __syncthreads();

    gemm_ldsA<256, 1, true, true>(A, wb_fc + (size_t)sh * 32768, fc_b + sh * H_,
                                  buf0, x_shb + ((size_t)sh * B_ + b0) * H_, lane);
    gemm_ldsA<128, 1, true, false>(buf0, wb_qa + (size_t)sh * 16384, qa_b + sh * H_,
                                   buf0, nullptr, lane);
    gemm_ldsA<128, 0, false, true>(buf0, wb_aW + (size_t)kh * 16384, nullptr,
                                   nullptr, wh2b + ((size_t)sh * B_ + b0) * H_, lane);
}

// ---- K2: fused neighbor pipeline (R10 base + ka fusion). 64 KB LDS. ----
__global__ __launch_bounds__(512) void k_fused(
    const float* __restrict__ x, const int* __restrict__ nbr,
    const short* __restrict__ wb_fc, const float* __restrict__ fc_b,
    const short* __restrict__ wb_v,  const float* __restrict__ v_b,
    const short* __restrict__ wb_ka, const float* __restrict__ ka_b,
    const short* __restrict__ x_shb, const short* __restrict__ wh2b,
    float* __restrict__ out_sbd)
{
    const int t = threadIdx.x, lane = t & 63, w = t >> 6;   // 8 waves
    const int bt = blockIdx.x, s = blockIdx.y;
    const int r0 = bt * 64;
    const int b0 = bt * 4;
    const int wr = w >> 2, wc = w & 3;

    __shared__ __align__(16) short A[64 * 256];    // 32 KB gathered neighbors
    __shared__ __align__(16) short Yt[64 * 128];   // 16 KB (Y, then H1 in-place)
    __shared__ __align__(16) short VH[64 * 128];   // 16 KB

    // gather 64 neighbor rows; 8 threads per row, 32 f32 each
    {
        const int row = t >> 3, q = t & 7;
        const int g = nbr[(size_t)s * (B_ * M_) + r0 + row];
        const float* xr = x + (size_t)g * IN_ + q * 32;
        short* arow = A + row * 256;
        const int key = (row & 7) << 3;
#pragma unroll
        for (int j = 0; j < 8; ++j) {
            float4 u = *(const float4*)(xr + j * 4);
            const int c = q * 32 + j * 4;
            s16x4 p; p.x = f2b(u.x); p.y = f2b(u.y); p.z = f2b(u.z); p.w = f2b(u.w);
            *(s16x4*)(arow + (c ^ key)) = p;
        }
    }
    __syncthreads();

    const int rbase = wr * 32, colb = wc * 32;

    for (int h = 0; h < HN_; ++h) {
        const int sh = s * HN_ + h;

        // G1: Y = lrelu(fc(A))
        tile_gemm256<1>(A, wb_fc + (size_t)sh * 32768, fc_b + sh * H_, Yt, lane, rbase, colb);
        __syncthreads();
        // G_V: Vh = v(Y) -> VH ; G_KA: H1 = lrelu(ka(Y)) in-place over Yt (midbar)
        tile_gemm128<0, false>(Yt, wb_v + (size_t)sh * 16384, v_b + sh * H_, VH, lane, rbase, colb);
        tile_gemm128<1, true>(Yt, wb_ka + (size_t)sh * 16384, ka_b + sh * H_, Yt, lane, rbase, colb);
        __syncthreads();

        // scores + softmax + PV + merge. Wave w: b = b0 + (w&3), d-half = w>>2.
        {
            const int b_loc = w & 3, dhalf = w >> 2;
            const int b = b0 + b_loc;
            const short* wrow = wh2b + ((size_t)sh * B_ + b) * H_;
            const int mloc = lane >> 2;
            const int row  = b_loc * 16 + mloc;
            const int key  = (mloc & 7) << 3;
            float sc = 0.f;
#pragma unroll
            for (int j8 = 0; j8 < 4; ++j8) {
                const int c = (lane & 3) * 32 + j8 * 8;
                bf16x8 hv = *(const bf16x8*)(Yt + row * 128 + (c ^ key));   // H1
                bf16x8 wv = *(const bf16x8*)(wrow + c);
#pragma unroll
                for (int e2 = 0; e2 < 8; ++e2) sc += b2f(hv[e2]) * b2f(wv[e2]);
            }
            sc += __shfl_xor(sc, 1);
            sc += __shfl_xor(sc, 2);
            float mx = sc;
            mx = fmaxf(mx, __shfl_xor(mx, 4));
            mx = fmaxf(mx, __shfl_xor(mx, 8));
            mx = fmaxf(mx, __shfl_xor(mx, 16));
            mx = fmaxf(mx, __shfl_xor(mx, 32));
            const float es = expf(sc - mx);
            float ss = es;
            ss += __shfl_xor(ss, 4);
            ss += __shfl_xor(ss, 8);
            ss += __shfl_xor(ss, 16);
            ss += __shfl_xor(ss, 32);
            const float inv = 1.f / ss;

            const short* xrow = x_shb + ((size_t)sh * B_ + b) * H_;
            float* orow = out_sbd + ((size_t)s * B_ + b) * D_ + h * H_;
            const int d = dhalf * 64 + lane;
            float hacc = 0.f;
#pragma unroll
            for (int mm = 0; mm < 16; ++mm) {
                const float e_mm = __shfl(es, mm * 4) * inv;
                const float vv = b2f(VH[(b_loc * 16 + mm) * 128 + (d ^ ((mm & 7) << 3))]);
                hacc += lrelu(vv * e_mm);
            }
            orow[d] = (b2f(xrow[d]) + hacc) * 0.5f;
        }
        __syncthreads();   // protect Yt/VH before next head
    }
}

// ---- K3: semantic attention, transposed-weight coalesced ----
__global__ __launch_bounds__(256) void k_semantic(
    const float* __restrict__ out_sbd,
    const float* __restrict__ ipT, const float* __restrict__ ip1b,
    const float* __restrict__ ip2w,
    const float* __restrict__ bpT, const float* __restrict__ bp1b,
    const float* __restrict__ bp2w,
    float* __restrict__ out)
{
    const int b = blockIdx.x, t = threadIdx.x;
    const int h = t & 127, dh = t >> 7;
    __shared__ float zs[S_ * D_];
    __shared__ float red[2 * 128 * 8];
    __shared__ float mps[2 * D_];
    __shared__ float svals[8];
    __shared__ float beta_s[8];

    for (int idx = t; idx < S_ * D_ / 4; idx += 256) {
        int sidx = idx >> 7, c = idx & 127;
        ((float4*)zs)[idx] = ((const float4*)(out_sbd + ((size_t)sidx * B_ + b) * D_))[c];
    }
    __syncthreads();

    {
        float a0 = 0.f, a1 = 0.f, a2 = 0.f, a3 = 0.f, a4 = 0.f;
        const float* w0 = ipT + h;
        const float* w1 = ipT + 65536 + h;
        const int dbeg = dh * 256;
        for (int d = dbeg; d < dbeg + 256; ++d) {
            const float wv0 = w0[d * 128];
            const float wv1 = w1[d * 128];
            a0 += wv0 * zs[d];
            a1 += wv0 * zs[512 + d];
            a2 += wv1 * zs[1024 + d];
            a3 += wv1 * zs[1536 + d];
            a4 += wv1 * zs[2048 + d];
        }
        float* rr = red + (dh * 128 + h) * 8;
        rr[0] = a0; rr[1] = a1; rr[2] = a2; rr[3] = a3; rr[4] = a4;
    }
    __syncthreads();
    if (t < 128) {
#pragma unroll
        for (int p = 0; p < 5; ++p) {
            const int ki = (p < 2) ? 0 : 1;
            float tot = red[t * 8 + p] + red[(128 + t) * 8 + p] + ip1b[ki * 128 + t];
            red[t * 8 + p] = tanhf(tot) * ip2w[ki * 128 + t];
        }
    }
    __syncthreads();
    if (t < 64) {
#pragma unroll
        for (int p = 0; p < 5; ++p) {
            float v = red[t * 8 + p] + red[(t + 64) * 8 + p];
            v += __shfl_xor(v, 1);  v += __shfl_xor(v, 2);  v += __shfl_xor(v, 4);
            v += __shfl_xor(v, 8);  v += __shfl_xor(v, 16); v += __shfl_xor(v, 32);
            if (t == 0) svals[p] = v;
        }
    }
    __syncthreads();
    if (t == 0) {
        float mx = fmaxf(svals[0], svals[1]);
        float e0 = expf(svals[0] - mx), e1 = expf(svals[1] - mx);
        float iv = 1.f / (e0 + e1);
        beta_s[0] = e0 * iv; beta_s[1] = e1 * iv;
        mx = fmaxf(fmaxf(svals[2], svals[3]), svals[4]);
        e0 = expf(svals[2] - mx); e1 = expf(svals[3] - mx); float e2 = expf(svals[4] - mx);
        iv = 1.f / (e0 + e1 + e2);
        beta_s[2] = e0 * iv; beta_s[3] = e1 * iv; beta_s[4] = e2 * iv;
    }
    __syncthreads();
    for (int d = t; d < D_; d += 256) {
        mps[d]       = beta_s[0] * zs[d]        + beta_s[1] * zs[512 + d];
        mps[512 + d] = beta_s[2] * zs[1024 + d] + beta_s[3] * zs[1536 + d] + beta_s[4] * zs[2048 + d];
    }
    __syncthreads();

    {
        float c0 = 0.f, c1 = 0.f;
        const float* wb = bpT + h;
        const int dbeg = dh * 256;
        for (int d = dbeg; d < dbeg + 256; ++d) {
            const float wv = wb[d * 128];
            c0 += wv * mps[d];
            c1 += wv * mps[512 + d];
        }
        float* rr = red + (dh * 128 + h) * 8;
        rr[0] = c0; rr[1] = c1;
    }
    __syncthreads();
    if (t < 128) {
#pragma unroll
        for (int p = 0; p < 2; ++p) {
            float tot = red[t * 8 + p] + red[(128 + t) * 8 + p] + bp1b[t];
            red[t * 8 + p] = tanhf(tot) * bp2w[t];
        }
    }
    __syncthreads();
    if (t < 64) {
#pragma unroll
        for (int p = 0; p < 2; ++p) {
            float v = red[t * 8 + p] + red[(t + 64) * 8 + p];
            v += __shfl_xor(v, 1);  v += __shfl_xor(v, 2);  v += __shfl_xor(v, 4);
            v += __shfl_xor(v, 8);  v += __shfl_xor(v, 16); v += __shfl_xor(v, 32);
            if (t == 0) svals[p] = v;
        }
    }
    __syncthreads();
    if (t == 0) {
        float mx = fmaxf(svals[0], svals[1]);
        float e0 = expf(svals[0] - mx), e1 = expf(svals[1] - mx);
        float iv = 1.f / (e0 + e1);
        beta_s[0] = e0 * iv; beta_s[1] = e1 * iv;
    }
    __syncthreads();
    for (int d = t; d < D_; d += 256)
        out[(size_t)b * D_ + d] = beta_s[0] * mps[d] + beta_s[1] * mps[512 + d];
}

extern "C" void kernel_launch(void* const* d_in, const int* in_sizes, int n_in,
                              void* d_out, int out_size, void* d_ws, size_t ws_size,
                              hipStream_t stream)
{
    const float* x    = (const float*)d_in[0];
    const int*   tgt  = (const int*)d_in[1];
    const int*   nbr  = (const int*)d_in[2];
    const float* fc_w = (const float*)d_in[3];
    const float* fc_b = (const float*)d_in[4];
    const float* q_w  = (const float*)d_in[5];
    const float* q_b  = (const float*)d_in[6];
    const float* k_w  = (const float*)d_in[7];
    const float* k_b  = (const float*)d_in[8];
    const float* v_w  = (const float*)d_in[9];
    const float* v_b  = (const float*)d_in[10];
    const float* attW = (const float*)d_in[11];
    const float* a1w  = (const float*)d_in[12];
    const float* a1b  = (const float*)d_in[13];
    const float* a2w  = (const float*)d_in[14];
    const float* a2b  = (const float*)d_in[15];
    const float* ip1w = (const float*)d_in[16];
    const float* ip1b = (const float*)d_in[17];
    const float* ip2w = (const float*)d_in[18];
    const float* bp1w = (const float*)d_in[19];
    const float* bp1b = (const float*)d_in[20];
    const float* bp2w = (const float*)d_in[21];

    float* out = (float*)d_out;

    // ws layout: shorts first, then f32
    short* wb_fc = (short*)d_ws;               // 655,360
    short* wb_v  = wb_fc + 655360;             // 327,680
    short* wb_aW = wb_v + 327680;              // 131,072
    short* wb_ka = wb_aW + 131072;             // 327,680 (fused a1@k)
    short* wb_qa = wb_ka + 327680;             // 327,680 (fused a2@q)
    short* x_shb = wb_qa + 327680;             // 2,621,440
    short* wh2b  = x_shb + 2621440;            // 2,621,440
    float* ka_b  = (float*)(wh2b + 2621440);   // 2,560 f32
    float* qa_b  = ka_b + 2560;                // 2,560 f32
    float* out_sbd = qa_b + 2560;              // 2,621,440 f32
    float* ipT   = out_sbd + 2621440;          // 131,072 f32
    float* bpT   = ipT + 131072;               // 65,536 f32

    k_convert<<<dim3(640, 3), 256, 0, stream>>>(
        fc_w, v_w, attW, wb_fc, wb_v, wb_aW);
    k_fuse_w<<<dim3(20, 2), 256, 0, stream>>>(
        a1w, k_w, a1b, k_b, a2w, q_w, a2b, q_b, wb_ka, ka_b, wb_qa, qa_b);
    k_transpose<<<dim3(768), 256, 0, stream>>>(ip1w, bp1w, ipT, bpT);
    k_target<<<dim3(64, 5), 256, 0, stream>>>(
        x, tgt, wb_fc, fc_b, wb_qa, qa_b, wb_aW, x_shb, wh2b);
    k_fused<<<dim3(256, 5), 512, 0, stream>>>(
        x, nbr, wb_fc, fc_b, wb_v, v_b, wb_ka, ka_b, x_shb, wh2b, out_sbd);
    k_semantic<<<dim3(B_), 256, 0, stream>>>(
        out_sbd, ipT, ip1b, ip2w, bpT, bp1b, bp2w, out);
}